// Round 8
// baseline (324.524 us; speedup 1.0000x reference)
//
#include <hip/hip_runtime.h>
#include <math.h>

#define NBATCH 4
#define CIN    256
#define CBOT   128
#define NPIX   4096
#define NPART  4          // i-split; flash phase 32*4*4 = 512 blocks = 2/CU exact
#define NBLK   512
#define LOG2E  1.44269504f

typedef __attribute__((ext_vector_type(4))) float f32x4;
typedef __attribute__((ext_vector_type(8))) short bf16x8;

__device__ __forceinline__ unsigned short f2bf(float f) {
    union { float f; unsigned u; } v; v.f = f;
    unsigned r = (v.u + 0x7FFFu + ((v.u >> 16) & 1u)) >> 16;   // RNE
    return (unsigned short)r;
}

// Manual device-scope generational grid barrier (2 blocks/CU x 256 CU = grid
// => all blocks co-resident; ROCm's own grid.sync is the same software scheme).
__device__ __forceinline__ void gridbar(unsigned* cnt, unsigned* gen) {
    __syncthreads();
    if (threadIdx.x == 0) {
        unsigned g = __hip_atomic_load(gen, __ATOMIC_RELAXED, __HIP_MEMORY_SCOPE_AGENT);
        unsigned a = __hip_atomic_fetch_add(cnt, 1u, __ATOMIC_ACQ_REL, __HIP_MEMORY_SCOPE_AGENT);
        if (a == NBLK - 1u) {
            __hip_atomic_store(cnt, 0u, __ATOMIC_RELAXED, __HIP_MEMORY_SCOPE_AGENT);
            __hip_atomic_store(gen, g + 1u, __ATOMIC_RELEASE, __HIP_MEMORY_SCOPE_AGENT);
        } else {
            int spins = 0;
            while (__hip_atomic_load(gen, __ATOMIC_ACQUIRE, __HIP_MEMORY_SCOPE_AGENT) == g) {
                __builtin_amdgcn_s_sleep(2);
                if (++spins > (1 << 22)) break;   // failsafe: wrong-answer, not hang
            }
        }
    }
    __syncthreads();
}

// ---------------------------------------------------------------------------
// Kernel P: prep = weight cvt (fp32->bf16, Wk pre-scaled by log2 e) + X
// transpose (X[b][c][p] fp32 -> Xt[b][p][c] bf16) + barrier-state zeroing.
// grid (64, 5, 4): y<4 -> xt tiles; y==4 -> wcvt slice + bar init.
// ---------------------------------------------------------------------------
__global__ __launch_bounds__(256) void k_prep(
    const float* __restrict__ X,
    const float* __restrict__ Wq, const float* __restrict__ Wk,
    const float* __restrict__ Wv, const float* __restrict__ Wo,
    unsigned short* __restrict__ Xt, unsigned short* __restrict__ Wb,
    unsigned* __restrict__ Bar)
{
    __shared__ float T[64][65];
    const int tid = threadIdx.x;
    if (blockIdx.y == 4) {
        const int gid = blockIdx.z * 64 + blockIdx.x;   // 256 blocks in slice
        if (gid < 128) {
            const int f4 = (gid * 256 + tid) * 4;       // 131072 total elems
            const int reg = f4 >> 15, loc = f4 & 32767;
            const float* __restrict__ W = (reg == 0) ? Wq : (reg == 1) ? Wk
                                        : (reg == 2) ? Wv : Wo;
            const float sc = (reg == 1) ? LOG2E : 1.f;
            float4 v = *(const float4*)(W + loc);
            ushort4 u;
            u.x = f2bf(v.x * sc); u.y = f2bf(v.y * sc);
            u.z = f2bf(v.z * sc); u.w = f2bf(v.w * sc);
            *(ushort4*)&Wb[f4] = u;
        } else if (gid == 128 && tid < 8) {
            Bar[tid] = 0u;                              // zero barrier cnt/gen
        }
        return;
    }
    const int pbase = blockIdx.x * 64;
    const int c0    = blockIdx.y * 64;
    const int b     = blockIdx.z;
#pragma unroll
    for (int k = 0; k < 4; ++k) {
        int f = tid + 256 * k;
        int cl = f >> 4, p4 = (f & 15) << 2;
        float4 v = *(const float4*)(X + (size_t)b * CIN * NPIX + (size_t)(c0 + cl) * NPIX + pbase + p4);
        T[cl][p4 + 0] = v.x; T[cl][p4 + 1] = v.y;
        T[cl][p4 + 2] = v.z; T[cl][p4 + 3] = v.w;
    }
    __syncthreads();
#pragma unroll
    for (int k = 0; k < 4; ++k) {
        int f = tid + 256 * k;
        int p = f >> 4, c4 = (f & 15) << 2;
        ushort4 u;
        u.x = f2bf(T[c4 + 0][p]); u.y = f2bf(T[c4 + 1][p]);
        u.z = f2bf(T[c4 + 2][p]); u.w = f2bf(T[c4 + 3][p]);
        *(ushort4*)&Xt[((size_t)b * NPIX + pbase + p) * CIN + c0 + c4] = u;
    }
}

// ---------------------------------------------------------------------------
// Kernel M: mega-kernel, 512 blocks x 256 thr, 2 blocks/CU (all co-resident).
//   Phase B: fused QKV projection (LDS-free MFMA, bf16 weights)
//   Phase C: flash attention (32 j/wave, prefetch, exp2, l via ones-MFMA)
//   Phase D: out-proj + residual (partials combined in MFMA accumulator)
// Manual grid barrier between phases.  Xt/Opart alias (no __restrict__).
// ---------------------------------------------------------------------------
__global__ __launch_bounds__(256, 2) void k_mega(
    const unsigned short* Xt,
    const unsigned short* __restrict__ Wb,
    const float* __restrict__ bq, const float* __restrict__ bk,
    const float* __restrict__ bv,
    unsigned short* __restrict__ Qt, unsigned short* __restrict__ Kt,
    unsigned short* __restrict__ Vt,
    unsigned short* Opart, float* __restrict__ Lpart,
    const float* __restrict__ bo, const float* __restrict__ gamma,
    const float* __restrict__ X, float* __restrict__ Out,
    unsigned* Bar)
{
    __shared__ __align__(16) unsigned short Qs[64][136];  // flash [i][c] pad 8
    __shared__ __align__(16) unsigned short Vs[128][72];  // flash [c][i] pad 8
    __shared__ __align__(16) unsigned short Ps[128][72];  // flash [j][i] pad 8

    const int tid  = threadIdx.x;
    const int bid  = blockIdx.x;
    const int wv   = tid >> 6, lane = tid & 63;
    const int grp  = lane & 15, quad = lane >> 4;

    // ===================== Phase B: QKV projection =====================
    {
        const int pbase = (bid & 127) * 32;
        const int b     = bid >> 7;
        const unsigned short* Xb  = Xt + (size_t)b * NPIX * CIN;
        const unsigned short* __restrict__ Wqb = Wb;
        const unsigned short* __restrict__ Wkb = Wb + 32768;
        const unsigned short* __restrict__ Wvb = Wb + 65536;
        const int obase = 32 * wv;

        f32x4 aQ[2][2], aK[2][2], aV[2][2];
#pragma unroll
        for (int mt = 0; mt < 2; ++mt)
#pragma unroll
            for (int nt = 0; nt < 2; ++nt) {
                aQ[mt][nt] = (f32x4)0.f; aK[mt][nt] = (f32x4)0.f; aV[mt][nt] = (f32x4)0.f;
            }

        for (int ks = 0; ks < 8; ++ks) {
            bf16x8 bx[2];
#pragma unroll
            for (int nt = 0; nt < 2; ++nt)
                bx[nt] = *(const bf16x8*)&Xb[(size_t)(pbase + nt * 16 + grp) * CIN + ks * 32 + quad * 8];
            bf16x8 wq_[2], wk_[2], wv_[2];
#pragma unroll
            for (int mt = 0; mt < 2; ++mt) {
                const size_t roff = (size_t)(obase + mt * 16 + grp) * CIN + ks * 32 + quad * 8;
                wq_[mt] = *(const bf16x8*)&Wqb[roff];
                wk_[mt] = *(const bf16x8*)&Wkb[roff];
                wv_[mt] = *(const bf16x8*)&Wvb[roff];
            }
#pragma unroll
            for (int mt = 0; mt < 2; ++mt)
#pragma unroll
                for (int nt = 0; nt < 2; ++nt) {
                    aQ[mt][nt] = __builtin_amdgcn_mfma_f32_16x16x32_bf16(wq_[mt], bx[nt], aQ[mt][nt], 0, 0, 0);
                    aK[mt][nt] = __builtin_amdgcn_mfma_f32_16x16x32_bf16(wk_[mt], bx[nt], aK[mt][nt], 0, 0, 0);
                    aV[mt][nt] = __builtin_amdgcn_mfma_f32_16x16x32_bf16(bx[mt], wv_[nt], aV[mt][nt], 0, 0, 0);
                }
        }

        unsigned short* Qb_ = Qt + (size_t)b * NPIX * CBOT;
        unsigned short* Kb_ = Kt + (size_t)b * NPIX * CBOT;
#pragma unroll
        for (int mt = 0; mt < 2; ++mt) {
            int o0 = obase + mt * 16 + quad * 4;
            float b4q[4], b4k[4];
#pragma unroll
            for (int r = 0; r < 4; ++r) { b4q[r] = bq[o0 + r]; b4k[r] = bk[o0 + r] * LOG2E; }
#pragma unroll
            for (int nt = 0; nt < 2; ++nt) {
                int p = pbase + nt * 16 + grp;
                ushort4 uq, uk;
                uq.x = f2bf(aQ[mt][nt][0] + b4q[0]); uq.y = f2bf(aQ[mt][nt][1] + b4q[1]);
                uq.z = f2bf(aQ[mt][nt][2] + b4q[2]); uq.w = f2bf(aQ[mt][nt][3] + b4q[3]);
                uk.x = f2bf(aK[mt][nt][0] + b4k[0]); uk.y = f2bf(aK[mt][nt][1] + b4k[1]);
                uk.z = f2bf(aK[mt][nt][2] + b4k[2]); uk.w = f2bf(aK[mt][nt][3] + b4k[3]);
                *(ushort4*)&Qb_[(size_t)p * CBOT + o0] = uq;
                *(ushort4*)&Kb_[(size_t)p * CBOT + o0] = uk;
            }
        }
        unsigned short* Vb_ = Vt + (size_t)b * CBOT * NPIX;
#pragma unroll
        for (int nt = 0; nt < 2; ++nt) {
            int o = obase + nt * 16 + grp;
            float bb = bv[o];
#pragma unroll
            for (int mt = 0; mt < 2; ++mt) {
                int p0 = pbase + mt * 16 + quad * 4;
                ushort4 u;
                u.x = f2bf(aV[mt][nt][0] + bb); u.y = f2bf(aV[mt][nt][1] + bb);
                u.z = f2bf(aV[mt][nt][2] + bb); u.w = f2bf(aV[mt][nt][3] + bb);
                *(ushort4*)&Vb_[(size_t)o * NPIX + p0] = u;
            }
        }
    }

    gridbar(Bar, Bar + 1);

    // ===================== Phase C: flash attention =====================
    {
        const int jblk = (bid & 31) * 128;
        const int part = (bid >> 5) & 3;
        const int b    = bid >> 7;
        const int tbeg = part * (64 / NPART);
        const int tend = tbeg + (64 / NPART);
        const unsigned short* __restrict__ Qb = Qt + (size_t)b * NPIX * CBOT;
        const unsigned short* __restrict__ Kb = Kt + (size_t)b * NPIX * CBOT;
        const unsigned short* __restrict__ Vb = Vt + (size_t)b * CBOT * NPIX;

        bf16x8 aq[2][4];
#pragma unroll
        for (int set = 0; set < 2; ++set)
#pragma unroll
            for (int ks = 0; ks < 4; ++ks)
                aq[set][ks] = *(const bf16x8*)&Kb[
                    (size_t)(jblk + wv * 32 + set * 16 + grp) * CBOT + ks * 32 + quad * 8];

        bf16x8 bones;
#pragma unroll
        for (int t = 0; t < 8; ++t) bones[t] = (short)0x3F80;   // 1.0 bf16

        f32x4 o[2][8];
#pragma unroll
        for (int set = 0; set < 2; ++set)
#pragma unroll
            for (int ct = 0; ct < 8; ++ct) o[set][ct] = (f32x4)0.f;
        f32x4 lacc[2] = {(f32x4)0.f, (f32x4)0.f};

        const int qrow = tid >> 4, qch = tid & 15;
        const int vrow = tid >> 3, vch = tid & 7;
        bf16x8 qreg[4], vreg[4];
#pragma unroll
        for (int k = 0; k < 4; ++k) {
            qreg[k] = *(const bf16x8*)&Qb[(size_t)(tbeg * 64 + qrow + 16 * k) * CBOT + qch * 8];
            vreg[k] = *(const bf16x8*)&Vb[(size_t)(vrow + 32 * k) * NPIX + tbeg * 64 + vch * 8];
        }

        for (int it = tbeg; it < tend; ++it) {
            __syncthreads();
#pragma unroll
            for (int k = 0; k < 4; ++k) {
                *(bf16x8*)&Qs[qrow + 16 * k][qch * 8] = qreg[k];
                *(bf16x8*)&Vs[vrow + 32 * k][vch * 8] = vreg[k];
            }
            __syncthreads();
            if (it + 1 < tend) {
                const int i1 = (it + 1) * 64;
#pragma unroll
                for (int k = 0; k < 4; ++k) {
                    qreg[k] = *(const bf16x8*)&Qb[(size_t)(i1 + qrow + 16 * k) * CBOT + qch * 8];
                    vreg[k] = *(const bf16x8*)&Vb[(size_t)(vrow + 32 * k) * NPIX + i1 + vch * 8];
                }
            }

            f32x4 sf[2][4];
#pragma unroll
            for (int set = 0; set < 2; ++set)
#pragma unroll
                for (int nt = 0; nt < 4; ++nt) sf[set][nt] = (f32x4)0.f;
#pragma unroll
            for (int nt = 0; nt < 4; ++nt)
#pragma unroll
                for (int ks = 0; ks < 4; ++ks) {
                    bf16x8 bq_ = *(const bf16x8*)&Qs[nt * 16 + grp][ks * 32 + quad * 8];
                    sf[0][nt] = __builtin_amdgcn_mfma_f32_16x16x32_bf16(aq[0][ks], bq_, sf[0][nt], 0, 0, 0);
                    sf[1][nt] = __builtin_amdgcn_mfma_f32_16x16x32_bf16(aq[1][ks], bq_, sf[1][nt], 0, 0, 0);
                }

#pragma unroll
            for (int set = 0; set < 2; ++set)
#pragma unroll
                for (int nt = 0; nt < 4; ++nt)
#pragma unroll
                    for (int r = 0; r < 4; ++r)
                        Ps[wv * 32 + set * 16 + quad * 4 + r][nt * 16 + grp] =
                            f2bf(exp2f(sf[set][nt][r]));

            bf16x8 af[2][2];
#pragma unroll
            for (int set = 0; set < 2; ++set)
#pragma unroll
                for (int ks2 = 0; ks2 < 2; ++ks2)
                    af[set][ks2] = *(const bf16x8*)&Ps[wv * 32 + set * 16 + grp][ks2 * 32 + quad * 8];

#pragma unroll
            for (int ct = 0; ct < 8; ++ct)
#pragma unroll
                for (int ks2 = 0; ks2 < 2; ++ks2) {
                    bf16x8 bv_ = *(const bf16x8*)&Vs[ct * 16 + grp][ks2 * 32 + quad * 8];
                    o[0][ct] = __builtin_amdgcn_mfma_f32_16x16x32_bf16(af[0][ks2], bv_, o[0][ct], 0, 0, 0);
                    o[1][ct] = __builtin_amdgcn_mfma_f32_16x16x32_bf16(af[1][ks2], bv_, o[1][ct], 0, 0, 0);
                }
#pragma unroll
            for (int set = 0; set < 2; ++set) {
                lacc[set] = __builtin_amdgcn_mfma_f32_16x16x32_bf16(af[set][0], bones, lacc[set], 0, 0, 0);
                lacc[set] = __builtin_amdgcn_mfma_f32_16x16x32_bf16(af[set][1], bones, lacc[set], 0, 0, 0);
            }
        }

        unsigned short* Ob = Opart + ((size_t)(part * NBATCH + b) * NPIX + jblk) * CBOT;
#pragma unroll
        for (int set = 0; set < 2; ++set)
#pragma unroll
            for (int ct = 0; ct < 8; ++ct)
#pragma unroll
                for (int r = 0; r < 4; ++r)
                    Ob[(size_t)(wv * 32 + set * 16 + quad * 4 + r) * CBOT + ct * 16 + grp] =
                        f2bf(o[set][ct][r]);
        if (grp == 0) {
#pragma unroll
            for (int set = 0; set < 2; ++set)
#pragma unroll
                for (int r = 0; r < 4; ++r)
                    Lpart[(size_t)(part * NBATCH + b) * NPIX + jblk + wv * 32 + set * 16 + quad * 4 + r] =
                        lacc[set][r];
        }
    }

    gridbar(Bar, Bar + 1);

    // ===================== Phase D: out-proj + residual =====================
    {
        const int pbase = (bid & 127) * 32;
        const int b     = bid >> 7;
        const unsigned short* __restrict__ Wob = Wb + 98304;
        const int obase = 64 * wv;

        f32x4 acc[2][4];
#pragma unroll
        for (int mt = 0; mt < 2; ++mt)
#pragma unroll
            for (int nt = 0; nt < 4; ++nt) acc[mt][nt] = (f32x4)0.f;

        for (int ks = 0; ks < 4; ++ks) {
            bf16x8 bw[4];
#pragma unroll
            for (int nt = 0; nt < 4; ++nt)
                bw[nt] = *(const bf16x8*)&Wob[(size_t)(obase + nt * 16 + grp) * CBOT + ks * 32 + quad * 8];
#pragma unroll
            for (int mt = 0; mt < 2; ++mt) {
                int p = pbase + mt * 16 + grp;
#pragma unroll
                for (int part = 0; part < NPART; ++part) {
                    bf16x8 ao = *(const bf16x8*)&Opart[
                        ((size_t)(part * NBATCH + b) * NPIX + p) * CBOT + ks * 32 + quad * 8];
#pragma unroll
                    for (int nt = 0; nt < 4; ++nt)
                        acc[mt][nt] = __builtin_amdgcn_mfma_f32_16x16x32_bf16(ao, bw[nt], acc[mt][nt], 0, 0, 0);
                }
            }
        }

        float linv[2][4];
#pragma unroll
        for (int mt = 0; mt < 2; ++mt)
#pragma unroll
            for (int r = 0; r < 4; ++r) {
                int p = pbase + mt * 16 + quad * 4 + r;
                float ls = 0.f;
#pragma unroll
                for (int part = 0; part < NPART; ++part)
                    ls += Lpart[(size_t)(part * NBATCH + b) * NPIX + p];
                linv[mt][r] = 1.f / ls;
            }
        float g = gamma[0];
#pragma unroll
        for (int nt = 0; nt < 4; ++nt) {
            int o = obase + nt * 16 + grp;
            float bb = bo[o];
#pragma unroll
            for (int mt = 0; mt < 2; ++mt) {
                int p0 = pbase + mt * 16 + quad * 4;
                size_t base = (size_t)b * CIN * NPIX + (size_t)o * NPIX + p0;
                float4 x4 = *(const float4*)(X + base);
                float4 r4;
                r4.x = g * (acc[mt][nt][0] * linv[mt][0] + bb) + x4.x;
                r4.y = g * (acc[mt][nt][1] * linv[mt][1] + bb) + x4.y;
                r4.z = g * (acc[mt][nt][2] * linv[mt][2] + bb) + x4.z;
                r4.w = g * (acc[mt][nt][3] * linv[mt][3] + bb) + x4.w;
                *(float4*)(Out + base) = r4;
            }
        }
    }
}

extern "C" void kernel_launch(void* const* d_in, const int* in_sizes, int n_in,
                              void* d_out, int out_size, void* d_ws, size_t ws_size,
                              hipStream_t stream)
{
    (void)in_sizes; (void)n_in; (void)out_size; (void)ws_size;
    const float* X     = (const float*)d_in[0];
    const float* Wq    = (const float*)d_in[1];
    const float* bq    = (const float*)d_in[2];
    const float* Wk    = (const float*)d_in[3];
    const float* bk    = (const float*)d_in[4];
    const float* Wv    = (const float*)d_in[5];
    const float* bv    = (const float*)d_in[6];
    const float* Wo    = (const float*)d_in[7];
    const float* bo    = (const float*)d_in[8];
    const float* gamma = (const float*)d_in[9];
    float* out = (float*)d_out;

    // ws: Qt|Kt|Vt bf16 4MB ea | Opart bf16 x4 16MB | Lpart 256KB | Wb 256KB | Bar
    // Xt (8MB) ALIASES Opart (consumed in phase B before phase C overwrites).
    const size_t BNC = (size_t)NBATCH * NPIX * CBOT;   // 2M elems
    unsigned short* Qt    = (unsigned short*)d_ws;
    unsigned short* Kt    = Qt + BNC;
    unsigned short* Vt    = Kt + BNC;
    unsigned short* Opart = Vt + BNC;
    unsigned short* Xt    = Opart;                      // alias (8MB <= 16MB)
    float*          Lpart = (float*)(Opart + (size_t)NPART * BNC);
    unsigned short* Wb    = (unsigned short*)(Lpart + (size_t)NPART * NBATCH * NPIX);
    unsigned*       Bar   = (unsigned*)(Wb + 131072);

    k_prep<<<dim3(64, 5, NBATCH), 256, 0, stream>>>(X, Wq, Wk, Wv, Wo, Xt, Wb, Bar);
    k_mega<<<dim3(NBLK), 256, 0, stream>>>(Xt, Wb, bq, bk, bv, Qt, Kt, Vt,
                                           Opart, Lpart, bo, gamma, X, out, Bar);
}

// Round 9
// 197.770 us; speedup vs baseline: 1.6409x; 1.6409x over previous
//
#include <hip/hip_runtime.h>
#include <math.h>

#define NBATCH 4
#define CIN    256
#define CBOT   128
#define NPIX   4096
#define LOG2E  1.44269504f

typedef __attribute__((ext_vector_type(4))) float f32x4;
typedef __attribute__((ext_vector_type(8))) short bf16x8;

__device__ __forceinline__ unsigned short f2bf(float f) {
    union { float f; unsigned u; } v; v.f = f;
    unsigned r = (v.u + 0x7FFFu + ((v.u >> 16) & 1u)) >> 16;   // RNE
    return (unsigned short)r;
}
// packed 2x bf16 (a low, b high) — HW v_cvt_pk_bf16_f32 when available
__device__ __forceinline__ unsigned pk2bf(float a, float b) {
#if __has_builtin(__builtin_amdgcn_cvt_pk_bf16_f32)
    auto r = __builtin_amdgcn_cvt_pk_bf16_f32(a, b);
    unsigned u; __builtin_memcpy(&u, &r, 4); return u;
#else
    return (unsigned)f2bf(a) | ((unsigned)f2bf(b) << 16);
#endif
}
__device__ __forceinline__ float fexp2(float x) {
#if __has_builtin(__builtin_amdgcn_exp2f)
    return __builtin_amdgcn_exp2f(x);
#else
    return exp2f(x);
#endif
}

// ---------------------------------------------------------------------------
// Kernel P: prep = weight cvt (fp32->bf16; Wk pre-scaled by log2 e; Wo stored
// with c-swizzle s=(c&15)*8+(c>>4) to match flash's swizzled Opart) + X
// transpose (X[b][c][p] fp32 -> Xt[b][p][c] bf16).
// grid (64, 5, 4): y<4 -> xt tiles; y==4 -> wcvt slice.
// ---------------------------------------------------------------------------
__global__ __launch_bounds__(256) void k_prep(
    const float* __restrict__ X,
    const float* __restrict__ Wq, const float* __restrict__ Wk,
    const float* __restrict__ Wv, const float* __restrict__ Wo,
    unsigned short* __restrict__ Xt, unsigned short* __restrict__ Wb)
{
    __shared__ float T[64][65];
    const int tid = threadIdx.x;
    if (blockIdx.y == 4) {
        const int gid = blockIdx.z * 64 + blockIdx.x;
        if (gid < 128) {
            const int f4 = (gid * 256 + tid) * 4;       // 131072 total elems
            const int reg = f4 >> 15, loc = f4 & 32767;
            if (reg < 3) {
                const float* __restrict__ W = (reg == 0) ? Wq : (reg == 1) ? Wk : Wv;
                const float sc = (reg == 1) ? LOG2E : 1.f;
                float4 v = *(const float4*)(W + loc);
                uint2 u;
                u.x = pk2bf(v.x * sc, v.y * sc);
                u.y = pk2bf(v.z * sc, v.w * sc);
                *(uint2*)&Wb[f4] = u;
            } else {
                // Wo with inverse c-swizzle: out[o][s] = Wo[o][(s&7)*16 + (s>>3)]
                const int o = loc >> 7, s0 = loc & 127;
                const int k = s0 >> 3, cb = s0 & 7;     // s0 % 4 == 0 so cb in {0,4}
                float w0 = Wo[o * CBOT + (cb + 0) * 16 + k];
                float w1 = Wo[o * CBOT + (cb + 1) * 16 + k];
                float w2 = Wo[o * CBOT + (cb + 2) * 16 + k];
                float w3 = Wo[o * CBOT + (cb + 3) * 16 + k];
                uint2 u; u.x = pk2bf(w0, w1); u.y = pk2bf(w2, w3);
                *(uint2*)&Wb[f4] = u;
            }
        }
        return;
    }
    const int pbase = blockIdx.x * 64;
    const int c0    = blockIdx.y * 64;
    const int b     = blockIdx.z;
#pragma unroll
    for (int k = 0; k < 4; ++k) {
        int f = tid + 256 * k;
        int cl = f >> 4, p4 = (f & 15) << 2;
        float4 v = *(const float4*)(X + (size_t)b * CIN * NPIX + (size_t)(c0 + cl) * NPIX + pbase + p4);
        T[cl][p4 + 0] = v.x; T[cl][p4 + 1] = v.y;
        T[cl][p4 + 2] = v.z; T[cl][p4 + 3] = v.w;
    }
    __syncthreads();
#pragma unroll
    for (int k = 0; k < 4; ++k) {
        int f = tid + 256 * k;
        int p = f >> 4, c4 = (f & 15) << 2;
        uint2 u;
        u.x = pk2bf(T[c4 + 0][p], T[c4 + 1][p]);
        u.y = pk2bf(T[c4 + 2][p], T[c4 + 3][p]);
        *(uint2*)&Xt[((size_t)b * NPIX + pbase + p) * CIN + c0 + c4] = u;
    }
}

// ---------------------------------------------------------------------------
// Kernel 1: fused Q+K+V projection, LDS-free MFMA, bf16 weights direct.
// grid (128 p-tiles of 32, 4 b), 256 thr = 4 waves (each: 32 o x 32 p).
// ---------------------------------------------------------------------------
__global__ __launch_bounds__(256) void k_qkv(
    const unsigned short* __restrict__ Xt,
    const unsigned short* __restrict__ Wb,
    const float* __restrict__ bq, const float* __restrict__ bk,
    const float* __restrict__ bv,
    unsigned short* __restrict__ Qt, unsigned short* __restrict__ Kt,
    unsigned short* __restrict__ Vt)
{
    const int tid = threadIdx.x;
    const int wv = tid >> 6, lane = tid & 63;
    const int grp = lane & 15, quad = lane >> 4;
    const int pbase = blockIdx.x * 32;
    const int b     = blockIdx.y;
    const unsigned short* __restrict__ Xb  = Xt + (size_t)b * NPIX * CIN;
    const unsigned short* __restrict__ Wqb = Wb;
    const unsigned short* __restrict__ Wkb = Wb + 32768;
    const unsigned short* __restrict__ Wvb = Wb + 65536;
    const int obase = 32 * wv;

    f32x4 aQ[2][2], aK[2][2], aV[2][2];
#pragma unroll
    for (int mt = 0; mt < 2; ++mt)
#pragma unroll
        for (int nt = 0; nt < 2; ++nt) {
            aQ[mt][nt] = (f32x4)0.f; aK[mt][nt] = (f32x4)0.f; aV[mt][nt] = (f32x4)0.f;
        }

    for (int ks = 0; ks < 8; ++ks) {
        bf16x8 bx[2];
#pragma unroll
        for (int nt = 0; nt < 2; ++nt)
            bx[nt] = *(const bf16x8*)&Xb[(size_t)(pbase + nt * 16 + grp) * CIN + ks * 32 + quad * 8];
        bf16x8 wq_[2], wk_[2], wv_[2];
#pragma unroll
        for (int mt = 0; mt < 2; ++mt) {
            const size_t roff = (size_t)(obase + mt * 16 + grp) * CIN + ks * 32 + quad * 8;
            wq_[mt] = *(const bf16x8*)&Wqb[roff];
            wk_[mt] = *(const bf16x8*)&Wkb[roff];
            wv_[mt] = *(const bf16x8*)&Wvb[roff];
        }
#pragma unroll
        for (int mt = 0; mt < 2; ++mt)
#pragma unroll
            for (int nt = 0; nt < 2; ++nt) {
                aQ[mt][nt] = __builtin_amdgcn_mfma_f32_16x16x32_bf16(wq_[mt], bx[nt], aQ[mt][nt], 0, 0, 0);
                aK[mt][nt] = __builtin_amdgcn_mfma_f32_16x16x32_bf16(wk_[mt], bx[nt], aK[mt][nt], 0, 0, 0);
                aV[mt][nt] = __builtin_amdgcn_mfma_f32_16x16x32_bf16(bx[mt], wv_[nt], aV[mt][nt], 0, 0, 0);
            }
    }

    unsigned short* Qb_ = Qt + (size_t)b * NPIX * CBOT;
    unsigned short* Kb_ = Kt + (size_t)b * NPIX * CBOT;
#pragma unroll
    for (int mt = 0; mt < 2; ++mt) {
        int o0 = obase + mt * 16 + quad * 4;
        float b4q[4], b4k[4];
#pragma unroll
        for (int r = 0; r < 4; ++r) { b4q[r] = bq[o0 + r]; b4k[r] = bk[o0 + r] * LOG2E; }
#pragma unroll
        for (int nt = 0; nt < 2; ++nt) {
            int p = pbase + nt * 16 + grp;
            uint2 uq, uk;
            uq.x = pk2bf(aQ[mt][nt][0] + b4q[0], aQ[mt][nt][1] + b4q[1]);
            uq.y = pk2bf(aQ[mt][nt][2] + b4q[2], aQ[mt][nt][3] + b4q[3]);
            uk.x = pk2bf(aK[mt][nt][0] + b4k[0], aK[mt][nt][1] + b4k[1]);
            uk.y = pk2bf(aK[mt][nt][2] + b4k[2], aK[mt][nt][3] + b4k[3]);
            *(uint2*)&Qb_[(size_t)p * CBOT + o0] = uq;
            *(uint2*)&Kb_[(size_t)p * CBOT + o0] = uk;
        }
    }
    unsigned short* Vb_ = Vt + (size_t)b * CBOT * NPIX;
#pragma unroll
    for (int nt = 0; nt < 2; ++nt) {
        int o = obase + nt * 16 + grp;
        float bb = bv[o];
#pragma unroll
        for (int mt = 0; mt < 2; ++mt) {
            int p0 = pbase + mt * 16 + quad * 4;
            uint2 u;
            u.x = pk2bf(aV[mt][nt][0] + bb, aV[mt][nt][1] + bb);
            u.y = pk2bf(aV[mt][nt][2] + bb, aV[mt][nt][3] + bb);
            *(uint2*)&Vb_[(size_t)o * NPIX + p0] = u;
        }
    }
}

// ---------------------------------------------------------------------------
// Kernel 2: flash attention. 32 j/wave (2 j-sets), register prefetch, exp2,
// l via ones-MFMA. LDS 50.5 KB -> 3 blocks/CU; grid (32, npart, 4).
// Opart stored c-SWIZZLED (s=(c&15)*8+(c>>4)) as vector stores; k_oproj's
// Wo uses the matching permutation (contraction-invariant).
// ---------------------------------------------------------------------------
__global__ __launch_bounds__(256, 3) void k_flash(
    const unsigned short* __restrict__ Qt,
    const unsigned short* __restrict__ Kt,
    const unsigned short* __restrict__ Vt,
    unsigned short* __restrict__ Opart,
    float* __restrict__ Lpart, int npart)
{
    __shared__ __align__(16) unsigned short Qs[64][132];  // [i][c] pad 4
    __shared__ __align__(16) unsigned short Vs[128][68];  // [c][i] pad 4
    __shared__ __align__(16) unsigned short Ps[128][68];  // [j][i] pad 4
    const int tid  = threadIdx.x;
    const int wv   = tid >> 6, lane = tid & 63;
    const int grp  = lane & 15, quad = lane >> 4;
    const int jblk = blockIdx.x * 128;
    const int part = blockIdx.y;
    const int b    = blockIdx.z;
    const int tbeg = (part * 64) / npart;
    const int tend = ((part + 1) * 64) / npart;
    const unsigned short* __restrict__ Qb = Qt + (size_t)b * NPIX * CBOT;
    const unsigned short* __restrict__ Kb = Kt + (size_t)b * NPIX * CBOT;
    const unsigned short* __restrict__ Vb = Vt + (size_t)b * CBOT * NPIX;

    bf16x8 aq[2][4];
#pragma unroll
    for (int set = 0; set < 2; ++set)
#pragma unroll
        for (int ks = 0; ks < 4; ++ks)
            aq[set][ks] = *(const bf16x8*)&Kb[
                (size_t)(jblk + wv * 32 + set * 16 + grp) * CBOT + ks * 32 + quad * 8];

    bf16x8 bones;
#pragma unroll
    for (int t = 0; t < 8; ++t) bones[t] = (short)0x3F80;   // 1.0 bf16

    f32x4 o[2][8];
#pragma unroll
    for (int set = 0; set < 2; ++set)
#pragma unroll
        for (int ct = 0; ct < 8; ++ct) o[set][ct] = (f32x4)0.f;
    f32x4 lacc[2] = {(f32x4)0.f, (f32x4)0.f};

    const int qrow = tid >> 4, qch = tid & 15;
    const int vrow = tid >> 3, vch = tid & 7;
    bf16x8 qreg[4], vreg[4];
#pragma unroll
    for (int k = 0; k < 4; ++k) {
        qreg[k] = *(const bf16x8*)&Qb[(size_t)(tbeg * 64 + qrow + 16 * k) * CBOT + qch * 8];
        vreg[k] = *(const bf16x8*)&Vb[(size_t)(vrow + 32 * k) * NPIX + tbeg * 64 + vch * 8];
    }

    for (int it = tbeg; it < tend; ++it) {
        __syncthreads();
#pragma unroll
        for (int k = 0; k < 4; ++k) {
            *(bf16x8*)&Qs[qrow + 16 * k][qch * 8] = qreg[k];
            *(bf16x8*)&Vs[vrow + 32 * k][vch * 8] = vreg[k];
        }
        __syncthreads();
        if (it + 1 < tend) {
            const int i1 = (it + 1) * 64;
#pragma unroll
            for (int k = 0; k < 4; ++k) {
                qreg[k] = *(const bf16x8*)&Qb[(size_t)(i1 + qrow + 16 * k) * CBOT + qch * 8];
                vreg[k] = *(const bf16x8*)&Vb[(size_t)(vrow + 32 * k) * NPIX + i1 + vch * 8];
            }
        }

        f32x4 sf[2][4];
#pragma unroll
        for (int set = 0; set < 2; ++set)
#pragma unroll
            for (int nt = 0; nt < 4; ++nt) sf[set][nt] = (f32x4)0.f;
#pragma unroll
        for (int nt = 0; nt < 4; ++nt)
#pragma unroll
            for (int ks = 0; ks < 4; ++ks) {
                bf16x8 bq_ = *(const bf16x8*)&Qs[nt * 16 + grp][ks * 32 + quad * 8];
                sf[0][nt] = __builtin_amdgcn_mfma_f32_16x16x32_bf16(aq[0][ks], bq_, sf[0][nt], 0, 0, 0);
                sf[1][nt] = __builtin_amdgcn_mfma_f32_16x16x32_bf16(aq[1][ks], bq_, sf[1][nt], 0, 0, 0);
            }

        // p = 2^s (Kt pre-scaled); pack pairs along r, write lo/hi halves
#pragma unroll
        for (int set = 0; set < 2; ++set) {
            const int rbase = wv * 32 + set * 16 + quad * 4;
#pragma unroll
            for (int nt = 0; nt < 4; ++nt) {
                const int col = nt * 16 + grp;
                unsigned u01 = pk2bf(fexp2(sf[set][nt][0]), fexp2(sf[set][nt][1]));
                unsigned u23 = pk2bf(fexp2(sf[set][nt][2]), fexp2(sf[set][nt][3]));
                Ps[rbase + 0][col] = (unsigned short)u01;
                Ps[rbase + 1][col] = (unsigned short)(u01 >> 16);
                Ps[rbase + 2][col] = (unsigned short)u23;
                Ps[rbase + 3][col] = (unsigned short)(u23 >> 16);
            }
        }

        bf16x8 af[2][2];
#pragma unroll
        for (int set = 0; set < 2; ++set)
#pragma unroll
            for (int ks2 = 0; ks2 < 2; ++ks2)
                af[set][ks2] = *(const bf16x8*)&Ps[wv * 32 + set * 16 + grp][ks2 * 32 + quad * 8];

#pragma unroll
        for (int ct = 0; ct < 8; ++ct)
#pragma unroll
            for (int ks2 = 0; ks2 < 2; ++ks2) {
                bf16x8 bv_ = *(const bf16x8*)&Vs[ct * 16 + grp][ks2 * 32 + quad * 8];
                o[0][ct] = __builtin_amdgcn_mfma_f32_16x16x32_bf16(af[0][ks2], bv_, o[0][ct], 0, 0, 0);
                o[1][ct] = __builtin_amdgcn_mfma_f32_16x16x32_bf16(af[1][ks2], bv_, o[1][ct], 0, 0, 0);
            }
#pragma unroll
        for (int set = 0; set < 2; ++set) {
            lacc[set] = __builtin_amdgcn_mfma_f32_16x16x32_bf16(af[set][0], bones, lacc[set], 0, 0, 0);
            lacc[set] = __builtin_amdgcn_mfma_f32_16x16x32_bf16(af[set][1], bones, lacc[set], 0, 0, 0);
        }
    }

    // swizzled store: lane's 8 ct-values are contiguous at s = grp*8 + ct
    unsigned short* Ob = Opart + ((size_t)(part * NBATCH + b) * NPIX + jblk) * CBOT;
#pragma unroll
    for (int set = 0; set < 2; ++set)
#pragma unroll
        for (int r = 0; r < 4; ++r) {
            const int row = wv * 32 + set * 16 + quad * 4 + r;
            uint4 u;
            u.x = pk2bf(o[set][0][r], o[set][1][r]);
            u.y = pk2bf(o[set][2][r], o[set][3][r]);
            u.z = pk2bf(o[set][4][r], o[set][5][r]);
            u.w = pk2bf(o[set][6][r], o[set][7][r]);
            *(uint4*)&Ob[(size_t)row * CBOT + grp * 8] = u;
        }
    if (grp == 0) {
#pragma unroll
        for (int set = 0; set < 2; ++set)
#pragma unroll
            for (int r = 0; r < 4; ++r)
                Lpart[(size_t)(part * NBATCH + b) * NPIX + jblk + wv * 32 + set * 16 + quad * 4 + r] =
                    lacc[set][r];
    }
}

// ---------------------------------------------------------------------------
// Kernel 3: out-proj + residual; partials combined IN the MFMA accumulator.
// Opart/Wo both c-swizzled => contraction unchanged. grid (128, 4 b).
// ---------------------------------------------------------------------------
__global__ __launch_bounds__(256) void k_oproj(
    const unsigned short* __restrict__ Opart, const float* __restrict__ Lpart,
    const unsigned short* __restrict__ Wob, const float* __restrict__ bo,
    const float* __restrict__ gamma, const float* __restrict__ X,
    float* __restrict__ Out, int npart)
{
    const int tid = threadIdx.x;
    const int wv = tid >> 6, lane = tid & 63;
    const int grp = lane & 15, quad = lane >> 4;
    const int pbase = blockIdx.x * 32;
    const int b     = blockIdx.y;
    const int obase = 64 * wv;

    f32x4 acc[2][4];
#pragma unroll
    for (int mt = 0; mt < 2; ++mt)
#pragma unroll
        for (int nt = 0; nt < 4; ++nt) acc[mt][nt] = (f32x4)0.f;

    for (int ks = 0; ks < 4; ++ks) {
        bf16x8 bw[4];
#pragma unroll
        for (int nt = 0; nt < 4; ++nt)
            bw[nt] = *(const bf16x8*)&Wob[(size_t)(obase + nt * 16 + grp) * CBOT + ks * 32 + quad * 8];
#pragma unroll
        for (int mt = 0; mt < 2; ++mt) {
            int p = pbase + mt * 16 + grp;
            for (int part = 0; part < npart; ++part) {
                bf16x8 ao = *(const bf16x8*)&Opart[
                    ((size_t)(part * NBATCH + b) * NPIX + p) * CBOT + ks * 32 + quad * 8];
#pragma unroll
                for (int nt = 0; nt < 4; ++nt)
                    acc[mt][nt] = __builtin_amdgcn_mfma_f32_16x16x32_bf16(ao, bw[nt], acc[mt][nt], 0, 0, 0);
            }
        }
    }

    float linv[2][4];
#pragma unroll
    for (int mt = 0; mt < 2; ++mt)
#pragma unroll
        for (int r = 0; r < 4; ++r) {
            int p = pbase + mt * 16 + quad * 4 + r;
            float ls = 0.f;
            for (int part = 0; part < npart; ++part)
                ls += Lpart[(size_t)(part * NBATCH + b) * NPIX + p];
            linv[mt][r] = 1.f / ls;
        }
    float g = gamma[0];
#pragma unroll
    for (int nt = 0; nt < 4; ++nt) {
        int o = obase + nt * 16 + grp;
        float bb = bo[o];
#pragma unroll
        for (int mt = 0; mt < 2; ++mt) {
            int p0 = pbase + mt * 16 + quad * 4;
            size_t base = (size_t)b * CIN * NPIX + (size_t)o * NPIX + p0;
            float4 x4 = *(const float4*)(X + base);
            float4 r4;
            r4.x = g * (acc[mt][nt][0] * linv[mt][0] + bb) + x4.x;
            r4.y = g * (acc[mt][nt][1] * linv[mt][1] + bb) + x4.y;
            r4.z = g * (acc[mt][nt][2] * linv[mt][2] + bb) + x4.z;
            r4.w = g * (acc[mt][nt][3] * linv[mt][3] + bb) + x4.w;
            *(float4*)(Out + base) = r4;
        }
    }
}

extern "C" void kernel_launch(void* const* d_in, const int* in_sizes, int n_in,
                              void* d_out, int out_size, void* d_ws, size_t ws_size,
                              hipStream_t stream)
{
    (void)in_sizes; (void)n_in; (void)out_size;
    const float* X     = (const float*)d_in[0];
    const float* Wq    = (const float*)d_in[1];
    const float* bq    = (const float*)d_in[2];
    const float* Wk    = (const float*)d_in[3];
    const float* bk    = (const float*)d_in[4];
    const float* Wv    = (const float*)d_in[5];
    const float* bv    = (const float*)d_in[6];
    const float* Wo    = (const float*)d_in[7];
    const float* bo    = (const float*)d_in[8];
    const float* gamma = (const float*)d_in[9];
    float* out = (float*)d_out;

    // ws layout: Qt|Kt|Vt (4MB ea) | Lpart (6 parts, 384KB) | Wb (256KB) |
    //            Opart (npart*4MB, last). Xt (8MB) aliases Opart.
    const size_t BNC = (size_t)NBATCH * NPIX * CBOT;   // 2M elems
    unsigned short* Qt    = (unsigned short*)d_ws;
    unsigned short* Kt    = Qt + BNC;
    unsigned short* Vt    = Kt + BNC;
    float*          Lpart = (float*)(Vt + BNC);
    unsigned short* Wb    = (unsigned short*)(Lpart + (size_t)6 * NBATCH * NPIX);
    unsigned short* Opart = Wb + 131072;
    unsigned short* Xt    = Opart;                      // alias (8MB <= npart*4MB)
    const size_t base_bytes = (size_t)((char*)Opart - (char*)d_ws);
    const int npart = (ws_size >= base_bytes + 6 * BNC * 2) ? 6 : 4;

    k_prep <<<dim3(64, 5, NBATCH),      256, 0, stream>>>(X, Wq, Wk, Wv, Wo, Xt, Wb);
    k_qkv  <<<dim3(128, NBATCH),        256, 0, stream>>>(Xt, Wb, bq, bk, bv, Qt, Kt, Vt);
    k_flash<<<dim3(32, npart, NBATCH),  256, 0, stream>>>(Qt, Kt, Vt, Opart, Lpart, npart);
    k_oproj<<<dim3(128, NBATCH),        256, 0, stream>>>(Opart, Lpart, Wb + 98304, bo, gamma, X, out, npart);
}

// Round 10
// 160.812 us; speedup vs baseline: 2.0180x; 1.2298x over previous
//
#include <hip/hip_runtime.h>
#include <math.h>

#define NBATCH 4
#define CIN    256
#define CBOT   128
#define NPIX   4096
#define NPART  4          // i-split; flash grid 32*4*4 = 512 = 2 blocks/CU exact
#define LOG2E  1.44269504f

typedef __attribute__((ext_vector_type(4))) float f32x4;
typedef __attribute__((ext_vector_type(8))) short bf16x8;

__device__ __forceinline__ unsigned short f2bf(float f) {
    union { float f; unsigned u; } v; v.f = f;
    unsigned r = (v.u + 0x7FFFu + ((v.u >> 16) & 1u)) >> 16;   // RNE
    return (unsigned short)r;
}
// packed 2x bf16 (a low, b high) — HW v_cvt_pk_bf16_f32 when available
__device__ __forceinline__ unsigned pk2bf(float a, float b) {
#if __has_builtin(__builtin_amdgcn_cvt_pk_bf16_f32)
    auto r = __builtin_amdgcn_cvt_pk_bf16_f32(a, b);
    unsigned u; __builtin_memcpy(&u, &r, 4); return u;
#else
    return (unsigned)f2bf(a) | ((unsigned)f2bf(b) << 16);
#endif
}
__device__ __forceinline__ float fexp2(float x) {
#if __has_builtin(__builtin_amdgcn_exp2f)
    return __builtin_amdgcn_exp2f(x);
#else
    return exp2f(x);
#endif
}

// ---------------------------------------------------------------------------
// Kernel W: weights fp32 -> bf16 once. Layout Wq|Wk|Wv|Wo row-major, 32768 ea.
// Wk pre-scaled by log2(e). grid (128), 256 thr.
// ---------------------------------------------------------------------------
__global__ __launch_bounds__(256) void k_wcvt(
    const float* __restrict__ Wq, const float* __restrict__ Wk,
    const float* __restrict__ Wv, const float* __restrict__ Wo,
    unsigned short* __restrict__ Wb)
{
    const int f4 = (blockIdx.x * 256 + threadIdx.x) * 4;   // 131072 total elems
    const int reg = f4 >> 15, loc = f4 & 32767;
    const float* __restrict__ W = (reg == 0) ? Wq : (reg == 1) ? Wk : (reg == 2) ? Wv : Wo;
    const float sc = (reg == 1) ? LOG2E : 1.f;
    float4 v = *(const float4*)(W + loc);
    uint2 u;
    u.x = pk2bf(v.x * sc, v.y * sc);
    u.y = pk2bf(v.z * sc, v.w * sc);
    *(uint2*)&Wb[f4] = u;
}

// ---------------------------------------------------------------------------
// Kernel 1: fused X-transpose + Q/K/V projection (no global Xt).
// Each block stages X[b][0:256][pbase:pbase+32] fp32 -> LDS bf16 [p][c],
// then the LDS-free MFMA QKV loop reads b128 frags from LDS.
// grid (128 p-tiles of 32, 4 b), 256 thr = 4 waves (each: 32 o x 32 p).
// ---------------------------------------------------------------------------
__global__ __launch_bounds__(256) void k_qkvx(
    const float* __restrict__ X,
    const unsigned short* __restrict__ Wb,
    const float* __restrict__ bq, const float* __restrict__ bk,
    const float* __restrict__ bv,
    unsigned short* __restrict__ Qt, unsigned short* __restrict__ Kt,
    unsigned short* __restrict__ Vt)
{
    __shared__ __align__(16) unsigned short Xs[32][264];  // [p_local][c], pad 8
    const int tid = threadIdx.x;
    const int wv = tid >> 6, lane = tid & 63;
    const int grp = lane & 15, quad = lane >> 4;
    const int pbase = blockIdx.x * 32;
    const int b     = blockIdx.y;
    const float* __restrict__ Xg = X + (size_t)b * CIN * NPIX + pbase;

    // stage: f = c*8 + pg; load float4 (4 consecutive pixels), scatter-transpose
#pragma unroll
    for (int k = 0; k < 8; ++k) {
        int f = tid + 256 * k;
        int c = f >> 3, pg = (f & 7) << 2;
        float4 v = *(const float4*)(Xg + (size_t)c * NPIX + pg);
        Xs[pg + 0][c] = f2bf(v.x);
        Xs[pg + 1][c] = f2bf(v.y);
        Xs[pg + 2][c] = f2bf(v.z);
        Xs[pg + 3][c] = f2bf(v.w);
    }
    __syncthreads();

    const unsigned short* __restrict__ Wqb = Wb;
    const unsigned short* __restrict__ Wkb = Wb + 32768;
    const unsigned short* __restrict__ Wvb = Wb + 65536;
    const int obase = 32 * wv;

    f32x4 aQ[2][2], aK[2][2], aV[2][2];
#pragma unroll
    for (int mt = 0; mt < 2; ++mt)
#pragma unroll
        for (int nt = 0; nt < 2; ++nt) {
            aQ[mt][nt] = (f32x4)0.f; aK[mt][nt] = (f32x4)0.f; aV[mt][nt] = (f32x4)0.f;
        }

    for (int ks = 0; ks < 8; ++ks) {
        bf16x8 bx[2];
#pragma unroll
        for (int nt = 0; nt < 2; ++nt)
            bx[nt] = *(const bf16x8*)&Xs[nt * 16 + grp][ks * 32 + quad * 8];
        bf16x8 wq_[2], wk_[2], wv_[2];
#pragma unroll
        for (int mt = 0; mt < 2; ++mt) {
            const size_t roff = (size_t)(obase + mt * 16 + grp) * CIN + ks * 32 + quad * 8;
            wq_[mt] = *(const bf16x8*)&Wqb[roff];
            wk_[mt] = *(const bf16x8*)&Wkb[roff];
            wv_[mt] = *(const bf16x8*)&Wvb[roff];
        }
#pragma unroll
        for (int mt = 0; mt < 2; ++mt)
#pragma unroll
            for (int nt = 0; nt < 2; ++nt) {
                aQ[mt][nt] = __builtin_amdgcn_mfma_f32_16x16x32_bf16(wq_[mt], bx[nt], aQ[mt][nt], 0, 0, 0);
                aK[mt][nt] = __builtin_amdgcn_mfma_f32_16x16x32_bf16(wk_[mt], bx[nt], aK[mt][nt], 0, 0, 0);
                aV[mt][nt] = __builtin_amdgcn_mfma_f32_16x16x32_bf16(bx[mt], wv_[nt], aV[mt][nt], 0, 0, 0);
            }
    }

    // Q, K stores: transposed [p][o], bias added (bk scaled by log2 e).
    unsigned short* Qb_ = Qt + (size_t)b * NPIX * CBOT;
    unsigned short* Kb_ = Kt + (size_t)b * NPIX * CBOT;
#pragma unroll
    for (int mt = 0; mt < 2; ++mt) {
        int o0 = obase + mt * 16 + quad * 4;
        float b4q[4], b4k[4];
#pragma unroll
        for (int r = 0; r < 4; ++r) { b4q[r] = bq[o0 + r]; b4k[r] = bk[o0 + r] * LOG2E; }
#pragma unroll
        for (int nt = 0; nt < 2; ++nt) {
            int p = pbase + nt * 16 + grp;
            uint2 uq, uk;
            uq.x = pk2bf(aQ[mt][nt][0] + b4q[0], aQ[mt][nt][1] + b4q[1]);
            uq.y = pk2bf(aQ[mt][nt][2] + b4q[2], aQ[mt][nt][3] + b4q[3]);
            uk.x = pk2bf(aK[mt][nt][0] + b4k[0], aK[mt][nt][1] + b4k[1]);
            uk.y = pk2bf(aK[mt][nt][2] + b4k[2], aK[mt][nt][3] + b4k[3]);
            *(uint2*)&Qb_[(size_t)p * CBOT + o0] = uq;
            *(uint2*)&Kb_[(size_t)p * CBOT + o0] = uk;
        }
    }
    // V store: natural [o][p], bias added.  (m=p, n=o)
    unsigned short* Vb_ = Vt + (size_t)b * CBOT * NPIX;
#pragma unroll
    for (int nt = 0; nt < 2; ++nt) {
        int o = obase + nt * 16 + grp;
        float bb = bv[o];
#pragma unroll
        for (int mt = 0; mt < 2; ++mt) {
            int p0 = pbase + mt * 16 + quad * 4;
            uint2 u;
            u.x = pk2bf(aV[mt][nt][0] + bb, aV[mt][nt][1] + bb);
            u.y = pk2bf(aV[mt][nt][2] + bb, aV[mt][nt][3] + bb);
            *(uint2*)&Vb_[(size_t)o * NPIX + p0] = u;
        }
    }
}

// ---------------------------------------------------------------------------
// Kernel 2: flash attention — R6-proven config. 32 j/wave, register prefetch,
// exp2 (Kt pre-scaled), l via ones-MFMA, scalar Opart epilogue.
// LDS 54.3 KB, 2 blocks/CU. grid (32, NPART, NBATCH), 256 thr = 4 waves.
// ---------------------------------------------------------------------------
__global__ __launch_bounds__(256, 2) void k_flash(
    const unsigned short* __restrict__ Qt,
    const unsigned short* __restrict__ Kt,
    const unsigned short* __restrict__ Vt,
    unsigned short* __restrict__ Opart,
    float* __restrict__ Lpart)
{
    __shared__ __align__(16) unsigned short Qs[64][136];  // [i][c] pad 8
    __shared__ __align__(16) unsigned short Vs[128][72];  // [c][i] pad 8
    __shared__ __align__(16) unsigned short Ps[128][72];  // [j][i] pad 8
    const int tid  = threadIdx.x;
    const int wv   = tid >> 6, lane = tid & 63;
    const int grp  = lane & 15, quad = lane >> 4;
    const int jblk = blockIdx.x * 128;
    const int part = blockIdx.y;
    const int b    = blockIdx.z;
    const int tbeg = part * (64 / NPART);
    const int tend = tbeg + (64 / NPART);
    const unsigned short* __restrict__ Qb = Qt + (size_t)b * NPIX * CBOT;
    const unsigned short* __restrict__ Kb = Kt + (size_t)b * NPIX * CBOT;
    const unsigned short* __restrict__ Vb = Vt + (size_t)b * CBOT * NPIX;

    bf16x8 aq[2][4];
#pragma unroll
    for (int set = 0; set < 2; ++set)
#pragma unroll
        for (int ks = 0; ks < 4; ++ks)
            aq[set][ks] = *(const bf16x8*)&Kb[
                (size_t)(jblk + wv * 32 + set * 16 + grp) * CBOT + ks * 32 + quad * 8];

    bf16x8 bones;
#pragma unroll
    for (int t = 0; t < 8; ++t) bones[t] = (short)0x3F80;   // 1.0 bf16

    f32x4 o[2][8];
#pragma unroll
    for (int set = 0; set < 2; ++set)
#pragma unroll
        for (int ct = 0; ct < 8; ++ct) o[set][ct] = (f32x4)0.f;
    f32x4 lacc[2] = {(f32x4)0.f, (f32x4)0.f};

    const int qrow = tid >> 4, qch = tid & 15;
    const int vrow = tid >> 3, vch = tid & 7;
    bf16x8 qreg[4], vreg[4];
#pragma unroll
    for (int k = 0; k < 4; ++k) {
        qreg[k] = *(const bf16x8*)&Qb[(size_t)(tbeg * 64 + qrow + 16 * k) * CBOT + qch * 8];
        vreg[k] = *(const bf16x8*)&Vb[(size_t)(vrow + 32 * k) * NPIX + tbeg * 64 + vch * 8];
    }

    for (int it = tbeg; it < tend; ++it) {
        __syncthreads();
#pragma unroll
        for (int k = 0; k < 4; ++k) {
            *(bf16x8*)&Qs[qrow + 16 * k][qch * 8] = qreg[k];
            *(bf16x8*)&Vs[vrow + 32 * k][vch * 8] = vreg[k];
        }
        __syncthreads();
        if (it + 1 < tend) {
            const int i1 = (it + 1) * 64;
#pragma unroll
            for (int k = 0; k < 4; ++k) {
                qreg[k] = *(const bf16x8*)&Qb[(size_t)(i1 + qrow + 16 * k) * CBOT + qch * 8];
                vreg[k] = *(const bf16x8*)&Vb[(size_t)(vrow + 32 * k) * NPIX + i1 + vch * 8];
            }
        }

        f32x4 sf[2][4];
#pragma unroll
        for (int set = 0; set < 2; ++set)
#pragma unroll
            for (int nt = 0; nt < 4; ++nt) sf[set][nt] = (f32x4)0.f;
#pragma unroll
        for (int nt = 0; nt < 4; ++nt)
#pragma unroll
            for (int ks = 0; ks < 4; ++ks) {
                bf16x8 bq_ = *(const bf16x8*)&Qs[nt * 16 + grp][ks * 32 + quad * 8];
                sf[0][nt] = __builtin_amdgcn_mfma_f32_16x16x32_bf16(aq[0][ks], bq_, sf[0][nt], 0, 0, 0);
                sf[1][nt] = __builtin_amdgcn_mfma_f32_16x16x32_bf16(aq[1][ks], bq_, sf[1][nt], 0, 0, 0);
            }

        // p = 2^s (Kt pre-scaled); pk2bf pairs, scalar LDS half-stores
#pragma unroll
        for (int set = 0; set < 2; ++set) {
            const int rbase = wv * 32 + set * 16 + quad * 4;
#pragma unroll
            for (int nt = 0; nt < 4; ++nt) {
                const int col = nt * 16 + grp;
                unsigned u01 = pk2bf(fexp2(sf[set][nt][0]), fexp2(sf[set][nt][1]));
                unsigned u23 = pk2bf(fexp2(sf[set][nt][2]), fexp2(sf[set][nt][3]));
                Ps[rbase + 0][col] = (unsigned short)u01;
                Ps[rbase + 1][col] = (unsigned short)(u01 >> 16);
                Ps[rbase + 2][col] = (unsigned short)u23;
                Ps[rbase + 3][col] = (unsigned short)(u23 >> 16);
            }
        }

        bf16x8 af[2][2];
#pragma unroll
        for (int set = 0; set < 2; ++set)
#pragma unroll
            for (int ks2 = 0; ks2 < 2; ++ks2)
                af[set][ks2] = *(const bf16x8*)&Ps[wv * 32 + set * 16 + grp][ks2 * 32 + quad * 8];

#pragma unroll
        for (int ct = 0; ct < 8; ++ct)
#pragma unroll
            for (int ks2 = 0; ks2 < 2; ++ks2) {
                bf16x8 bv_ = *(const bf16x8*)&Vs[ct * 16 + grp][ks2 * 32 + quad * 8];
                o[0][ct] = __builtin_amdgcn_mfma_f32_16x16x32_bf16(af[0][ks2], bv_, o[0][ct], 0, 0, 0);
                o[1][ct] = __builtin_amdgcn_mfma_f32_16x16x32_bf16(af[1][ks2], bv_, o[1][ct], 0, 0, 0);
            }
#pragma unroll
        for (int set = 0; set < 2; ++set) {
            lacc[set] = __builtin_amdgcn_mfma_f32_16x16x32_bf16(af[set][0], bones, lacc[set], 0, 0, 0);
            lacc[set] = __builtin_amdgcn_mfma_f32_16x16x32_bf16(af[set][1], bones, lacc[set], 0, 0, 0);
        }
    }

    // R6-style scalar epilogue stores (L2-merged; measured WRITE == data size)
    unsigned short* Ob = Opart + ((size_t)(part * NBATCH + b) * NPIX + jblk) * CBOT;
#pragma unroll
    for (int set = 0; set < 2; ++set)
#pragma unroll
        for (int ct = 0; ct < 8; ++ct)
#pragma unroll
            for (int r = 0; r < 4; ++r)
                Ob[(size_t)(wv * 32 + set * 16 + quad * 4 + r) * CBOT + ct * 16 + grp] =
                    f2bf(o[set][ct][r]);
    if (grp == 0) {
#pragma unroll
        for (int set = 0; set < 2; ++set)
#pragma unroll
            for (int r = 0; r < 4; ++r)
                Lpart[(size_t)(part * NBATCH + b) * NPIX + jblk + wv * 32 + set * 16 + quad * 4 + r] =
                    lacc[set][r];
    }
}

// ---------------------------------------------------------------------------
// Kernel 3: out-proj + residual; partials combined IN the MFMA accumulator.
// grid (128 p-tiles of 32, 4 b), 256 thr = 4 waves (n=64 o each).
// ---------------------------------------------------------------------------
__global__ __launch_bounds__(256) void k_oproj(
    const unsigned short* __restrict__ Opart, const float* __restrict__ Lpart,
    const unsigned short* __restrict__ Wob, const float* __restrict__ bo,
    const float* __restrict__ gamma, const float* __restrict__ X,
    float* __restrict__ Out)
{
    const int tid = threadIdx.x;
    const int wv = tid >> 6, lane = tid & 63;
    const int grp = lane & 15, quad = lane >> 4;
    const int pbase = blockIdx.x * 32;
    const int b     = blockIdx.y;
    const int obase = 64 * wv;

    f32x4 acc[2][4];
#pragma unroll
    for (int mt = 0; mt < 2; ++mt)
#pragma unroll
        for (int nt = 0; nt < 4; ++nt) acc[mt][nt] = (f32x4)0.f;

    for (int ks = 0; ks < 4; ++ks) {
        bf16x8 bw[4];
#pragma unroll
        for (int nt = 0; nt < 4; ++nt)
            bw[nt] = *(const bf16x8*)&Wob[(size_t)(obase + nt * 16 + grp) * CBOT + ks * 32 + quad * 8];
#pragma unroll
        for (int mt = 0; mt < 2; ++mt) {
            int p = pbase + mt * 16 + grp;
#pragma unroll
            for (int part = 0; part < NPART; ++part) {
                bf16x8 ao = *(const bf16x8*)&Opart[
                    ((size_t)(part * NBATCH + b) * NPIX + p) * CBOT + ks * 32 + quad * 8];
#pragma unroll
                for (int nt = 0; nt < 4; ++nt)
                    acc[mt][nt] = __builtin_amdgcn_mfma_f32_16x16x32_bf16(ao, bw[nt], acc[mt][nt], 0, 0, 0);
            }
        }
    }

    float linv[2][4];
#pragma unroll
    for (int mt = 0; mt < 2; ++mt)
#pragma unroll
        for (int r = 0; r < 4; ++r) {
            int p = pbase + mt * 16 + quad * 4 + r;
            float ls = 0.f;
#pragma unroll
            for (int part = 0; part < NPART; ++part)
                ls += Lpart[(size_t)(part * NBATCH + b) * NPIX + p];
            linv[mt][r] = 1.f / ls;
        }
    float g = gamma[0];
#pragma unroll
    for (int nt = 0; nt < 4; ++nt) {
        int o = obase + nt * 16 + grp;
        float bb = bo[o];
#pragma unroll
        for (int mt = 0; mt < 2; ++mt) {
            int p0 = pbase + mt * 16 + quad * 4;
            size_t base = (size_t)b * CIN * NPIX + (size_t)o * NPIX + p0;
            float4 x4 = *(const float4*)(X + base);
            float4 r4;
            r4.x = g * (acc[mt][nt][0] * linv[mt][0] + bb) + x4.x;
            r4.y = g * (acc[mt][nt][1] * linv[mt][1] + bb) + x4.y;
            r4.z = g * (acc[mt][nt][2] * linv[mt][2] + bb) + x4.z;
            r4.w = g * (acc[mt][nt][3] * linv[mt][3] + bb) + x4.w;
            *(float4*)(Out + base) = r4;
        }
    }
}

extern "C" void kernel_launch(void* const* d_in, const int* in_sizes, int n_in,
                              void* d_out, int out_size, void* d_ws, size_t ws_size,
                              hipStream_t stream)
{
    (void)in_sizes; (void)n_in; (void)out_size; (void)ws_size;
    const float* X     = (const float*)d_in[0];
    const float* Wq    = (const float*)d_in[1];
    const float* bq    = (const float*)d_in[2];
    const float* Wk    = (const float*)d_in[3];
    const float* bk    = (const float*)d_in[4];
    const float* Wv    = (const float*)d_in[5];
    const float* bv    = (const float*)d_in[6];
    const float* Wo    = (const float*)d_in[7];
    const float* bo    = (const float*)d_in[8];
    const float* gamma = (const float*)d_in[9];
    float* out = (float*)d_out;

    // ws: Qt|Kt|Vt bf16 4MB ea | Opart bf16 x4 16MB | Lpart 256KB | Wb 256KB
    // (no Xt anymore — transpose fused into k_qkvx; no aliasing)
    const size_t BNC = (size_t)NBATCH * NPIX * CBOT;   // 2M elems
    unsigned short* Qt    = (unsigned short*)d_ws;
    unsigned short* Kt    = Qt + BNC;
    unsigned short* Vt    = Kt + BNC;
    unsigned short* Opart = Vt + BNC;
    float*          Lpart = (float*)(Opart + (size_t)NPART * BNC);
    unsigned short* Wb    = (unsigned short*)(Lpart + (size_t)NPART * NBATCH * NPIX);

    k_wcvt <<<dim3(128),               256, 0, stream>>>(Wq, Wk, Wv, Wo, Wb);
    k_qkvx <<<dim3(128, NBATCH),       256, 0, stream>>>(X, Wb, bq, bk, bv, Qt, Kt, Vt);
    k_flash<<<dim3(32, NPART, NBATCH), 256, 0, stream>>>(Qt, Kt, Vt, Opart, Lpart);
    k_oproj<<<dim3(128, NBATCH),       256, 0, stream>>>(Opart, Lpart, Wb + 98304, bo, gamma, X, out);
}